// Round 6
// baseline (177.328 us; speedup 1.0000x reference)
//
#include <hip/hip_runtime.h>

typedef short bf16x8 __attribute__((ext_vector_type(8)));
typedef float f32x4 __attribute__((ext_vector_type(4)));
typedef unsigned short ushort_t;

// Problem constants
constexpr int NB   = 2;
constexpr int ICH  = 64;
constexpr int LDIM = 2744;   // 14^3
constexpr int LPAD = 2752;   // multiple of 32
constexpr int NHH  = 8;
constexpr int KCH  = LPAD / 8;   // 344 key-chunks for V layout

// q scale: 1/sqrt(32) * log2(e)  (exp2-domain softmax)
#define QSCL (0.17677669529663687f * 1.4426950408889634f)

// Workspace layout (float offsets)
// xs : [n][kc 8][pos 4096][8us]  (bf16 hi only)        -> 262144 f
// wt : [t 27][kc 16][oc 640][8us] (hi 0-7, lo 8-15)    -> 1105920 f
// qs : [nh 16][g 4][p 2752][8us]                       -> 704512 f
// ks : same                                            -> 704512 f
// vs : [nh 16][kc 344][dv 16][8us]                     -> 352256 f
// Oh : fp32 [n 2][128][2744]                           -> 702464 f
constexpr size_t XS_OFF = 0;
constexpr size_t WT_OFF = 262144;
constexpr size_t Q_OFF  = WT_OFF + 1105920;
constexpr size_t K_OFF  = Q_OFF + 704512;
constexpr size_t V_OFF  = K_OFF + 704512;
constexpr size_t OH_OFF = V_OFF + 352256;

__device__ __forceinline__ ushort_t bf16_rn(float x) {
    unsigned u = __float_as_uint(x);
    u += 0x7FFFu + ((u >> 16) & 1u);
    return (ushort_t)(u >> 16);
}
__device__ __forceinline__ float bf16_f(ushort_t h) {
    return __uint_as_float((unsigned)h << 16);
}
__device__ __forceinline__ float exp2_hw(float x) {
    float r;
    asm("v_exp_f32 %0, %1" : "=v"(r) : "v"(x));
    return r;
}
__device__ __forceinline__ unsigned cvt_pk_bf16(float lo, float hi) {
    unsigned r;
    asm("v_cvt_pk_bf16_f32 %0, %1, %2" : "=v"(r) : "v"(lo), "v"(hi));
    return r;
}

// ---------------------------------------------------------------------------
// 1. Pad + transpose x into chunked bf16 layout (hi only — 2-pass split).
__global__ __launch_bounds__(256) void pad_split_x_kernel(
        const float* __restrict__ x, ushort_t* __restrict__ xs) {
    int idx = blockIdx.x * 256 + threadIdx.x;      // 2*64*4096
    int n  = idx >> 18;
    int ic = (idx >> 12) & 63;
    int pos = idx & 4095;
    int z = pos >> 8, y = (pos >> 4) & 15, xx = pos & 15;
    float v = 0.f;
    if (z >= 1 && z <= 14 && y >= 1 && y <= 14 && xx >= 1 && xx <= 14)
        v = x[(n * 64 + ic) * LDIM + (z - 1) * 196 + (y - 1) * 14 + (xx - 1)];
    xs[((size_t)(n * 8 + (ic >> 3)) * 4096 + pos) * 8 + (ic & 7)] = bf16_rn(v);
}

// ---------------------------------------------------------------------------
// 2. Transpose + bf16-split weights (exact hi+lo) into chunked layout.
__global__ __launch_bounds__(256) void w_split_kernel(
        const float* __restrict__ w, ushort_t* __restrict__ wt) {
    int idx = blockIdx.x * 256 + threadIdx.x;      // 27*640*64
    int t = idx / 40960;
    int r = idx % 40960;
    int oc = r >> 6, ic = r & 63;
    float v = w[(oc * 64 + ic) * 27 + t];
    ushort_t hi = bf16_rn(v);
    float lo = v - bf16_f(hi);
    wt[((size_t)(t * 16 + (ic >> 3)) * 640 + oc) * 8 + (ic & 7)] = hi;
    wt[((size_t)(t * 16 + 8 + (ic >> 3)) * 640 + oc) * 8 + (ic & 7)] = bf16_rn(lo);
}

// ---------------------------------------------------------------------------
// 3. Conv as 27 shifted K=64 MFMA GEMM-accumulates, 2-pass split
//    (Wh·Xh + Wl·Xh; X rounded once). Wave tile 64oc x 64p, 2-wave blocks.
//    Software pipeline: A split hi/lo half-passes, B double-buffered a tap
//    ahead; every load batch is covered by a 32-MFMA burst.
__global__ __launch_bounds__(128) void conv_mfma_kernel(
        const ushort_t* __restrict__ xs, const ushort_t* __restrict__ wt,
        const float* __restrict__ b, ushort_t* __restrict__ qs,
        ushort_t* __restrict__ ks, ushort_t* __restrict__ vs) {
    const int n = blockIdx.z, ocg = blockIdx.y;
    const int wave = threadIdx.x >> 6, lane = threadIdx.x & 63;
    const int lq = lane & 15, g = lane >> 4;
    const int p0 = blockIdx.x * 128 + wave * 64;
    const int oc0 = ocg * 64;

    int posi[4], pcol[4];
#pragma unroll
    for (int ps = 0; ps < 4; ++ps) {
        int p = p0 + ps * 16 + lq;
        pcol[ps] = p;
        int pc = p < LDIM ? p : LDIM - 1;
        int z = pc / 196, rr = pc % 196, y = rr / 14, xx = rr % 14;
        posi[ps] = z * 256 + y * 16 + xx;
    }

    const bf16x8* XB = (const bf16x8*)xs + (size_t)n * 8 * 4096;
    const bf16x8* WB = (const bf16x8*)wt;
    const int ocl = oc0 + lq;

    f32x4 acc[4][4];
#pragma unroll
    for (int os = 0; os < 4; ++os)
#pragma unroll
        for (int ps = 0; ps < 4; ++ps)
            acc[os][ps] = (f32x4){0.f, 0.f, 0.f, 0.f};

    bf16x8 Ah[4][2], Al[4][2], Bc[4][2], Bn[4][2];

    // Prologue: A-hi(0), B(0)
#pragma unroll
    for (int os = 0; os < 4; ++os) {
        Ah[os][0] = WB[(size_t)(g) * 640 + ocl + os * 16];
        Ah[os][1] = WB[(size_t)(4 + g) * 640 + ocl + os * 16];
    }
#pragma unroll
    for (int ps = 0; ps < 4; ++ps) {
        Bc[ps][0] = XB[(size_t)(g) * 4096 + posi[ps]];
        Bc[ps][1] = XB[(size_t)(4 + g) * 4096 + posi[ps]];
    }

    for (int t = 0; t < 27; ++t) {
        const bf16x8* Wt = WB + (size_t)t * 16 * 640;
        // issue A-lo(t)
#pragma unroll
        for (int os = 0; os < 4; ++os) {
            Al[os][0] = Wt[(size_t)(8 + g) * 640 + ocl + os * 16];
            Al[os][1] = Wt[(size_t)(12 + g) * 640 + ocl + os * 16];
        }
        // issue B(t+1)
        if (t < 26) {
            const int tn = t + 1;
            const int tz = tn / 9, tr = tn % 9, ty = tr / 3, tx = tr % 3;
            const int toff = tz * 256 + ty * 16 + tx;
#pragma unroll
            for (int ps = 0; ps < 4; ++ps) {
                Bn[ps][0] = XB[(size_t)(g) * 4096 + posi[ps] + toff];
                Bn[ps][1] = XB[(size_t)(4 + g) * 4096 + posi[ps] + toff];
            }
        }
        // hi-pass MFMAs (covers the loads above)
#pragma unroll
        for (int os = 0; os < 4; ++os)
#pragma unroll
            for (int ps = 0; ps < 4; ++ps) {
                f32x4 a = acc[os][ps];
                a = __builtin_amdgcn_mfma_f32_16x16x32_bf16(Ah[os][0], Bc[ps][0], a, 0, 0, 0);
                a = __builtin_amdgcn_mfma_f32_16x16x32_bf16(Ah[os][1], Bc[ps][1], a, 0, 0, 0);
                acc[os][ps] = a;
            }
        // issue A-hi(t+1) into now-dead Ah
        if (t < 26) {
            const bf16x8* Wn = WB + (size_t)(t + 1) * 16 * 640;
#pragma unroll
            for (int os = 0; os < 4; ++os) {
                Ah[os][0] = Wn[(size_t)(g) * 640 + ocl + os * 16];
                Ah[os][1] = Wn[(size_t)(4 + g) * 640 + ocl + os * 16];
            }
        }
        // lo-pass MFMAs (covers A-hi(t+1) loads)
#pragma unroll
        for (int os = 0; os < 4; ++os)
#pragma unroll
            for (int ps = 0; ps < 4; ++ps) {
                f32x4 a = acc[os][ps];
                a = __builtin_amdgcn_mfma_f32_16x16x32_bf16(Al[os][0], Bc[ps][0], a, 0, 0, 0);
                a = __builtin_amdgcn_mfma_f32_16x16x32_bf16(Al[os][1], Bc[ps][1], a, 0, 0, 0);
                acc[os][ps] = a;
            }
        if (t < 26) {
#pragma unroll
            for (int ps = 0; ps < 4; ++ps) {
                Bc[ps][0] = Bn[ps][0];
                Bc[ps][1] = Bn[ps][1];
            }
        }
    }

    // Epilogue: bias + route to qs/ks/vs (block-uniform in ocg).
#pragma unroll
    for (int os = 0; os < 4; ++os) {
#pragma unroll
        for (int ps = 0; ps < 4; ++ps) {
            if (pcol[ps] >= LDIM) continue;
            const int p = pcol[ps];
#pragma unroll
            for (int i = 0; i < 4; ++i) {
                const int oc = oc0 + os * 16 + g * 4 + i;
                const float val = acc[os][ps][i] + b[oc];
                if (oc0 < 256) {          // q, pre-scaled into exp2 domain
                    const int h = oc >> 5, d = oc & 31;
                    qs[((size_t)((n * NHH + h) * 4 + (d >> 3)) * LPAD + p) * 8 + (d & 7)] =
                        bf16_rn(val * QSCL);
                } else if (oc0 < 512) {   // k
                    const int c = oc - 256, h = c >> 5, d = c & 31;
                    ks[((size_t)((n * NHH + h) * 4 + (d >> 3)) * LPAD + p) * 8 + (d & 7)] =
                        bf16_rn(val);
                } else {                  // v
                    const int c = oc - 512, h = c >> 4, dv = c & 15;
                    vs[((size_t)((n * NHH + h) * KCH + (p >> 3)) * 16 + dv) * 8 + (p & 7)] =
                        bf16_rn(val);
                }
            }
        }
    }
}

// ---------------------------------------------------------------------------
// 4. Flash attention, bf16 MFMA, no-max exp2 softmax, cvt_pk packing,
//    next-tile K/V register prefetch (unchanged from r5).
__global__ __launch_bounds__(256) void attn_mfma_kernel(
        const ushort_t* __restrict__ qs, const ushort_t* __restrict__ ks,
        const ushort_t* __restrict__ vs, float* __restrict__ Oh) {
    const int nh = blockIdx.y, n = nh >> 3, h = nh & 7;
    const int wave = threadIdx.x >> 6, lane = threadIdx.x & 63;
    const int lq = lane & 15, g = lane >> 4;
    const int q0 = blockIdx.x * 64 + wave * 16;

    const bf16x8* QS = (const bf16x8*)qs;
    const bf16x8 qf = QS[((size_t)nh * 4 + g) * LPAD + q0 + lq];
    const bf16x8* KS = (const bf16x8*)ks + (size_t)nh * 4 * LPAD + (size_t)g * LPAD;
    const bf16x8* VS = (const bf16x8*)vs + (size_t)nh * KCH * 16 + lq;

    f32x4 o = {0.f, 0.f, 0.f, 0.f};
    float s = 0.f;
    const int srcA = lq + 32 * (g & 1);
    const int srcB = srcA + 16;

    bf16x8 kA = KS[lq];
    bf16x8 kB = KS[16 + lq];
    bf16x8 vf = VS[(size_t)g * 16];

    for (int kb = 0; kb < LDIM; kb += 32) {
        const int nb = (kb + 32 < LDIM) ? kb + 32 : kb;   // prefetch (clamped)
        bf16x8 kAn = KS[nb + lq];
        bf16x8 kBn = KS[nb + 16 + lq];
        bf16x8 vfn = VS[(size_t)((nb >> 3) + g) * 16];

        const f32x4 z = {0.f, 0.f, 0.f, 0.f};
        f32x4 st0 = __builtin_amdgcn_mfma_f32_16x16x32_bf16(kA, qf, z, 0, 0, 0);
        f32x4 st1 = __builtin_amdgcn_mfma_f32_16x16x32_bf16(kB, qf, z, 0, 0, 0);

        float p0 = exp2_hw(st0[0]), p1 = exp2_hw(st0[1]);
        float p2 = exp2_hw(st0[2]), p3 = exp2_hw(st0[3]);
        float p4 = exp2_hw(st1[0]), p5 = exp2_hw(st1[1]);
        float p6 = exp2_hw(st1[2]), p7 = exp2_hw(st1[3]);

        if (kb + 32 > LDIM) {                 // mask tail keys (>= 2744)
            if (kb + 4 * g + 0  >= LDIM) p0 = 0.f;
            if (kb + 4 * g + 1  >= LDIM) p1 = 0.f;
            if (kb + 4 * g + 2  >= LDIM) p2 = 0.f;
            if (kb + 4 * g + 3  >= LDIM) p3 = 0.f;
            if (kb + 16 + 4 * g + 0 >= LDIM) p4 = 0.f;
            if (kb + 16 + 4 * g + 1 >= LDIM) p5 = 0.f;
            if (kb + 16 + 4 * g + 2 >= LDIM) p6 = 0.f;
            if (kb + 16 + 4 * g + 3 >= LDIM) p7 = 0.f;
        }

        s += ((p0 + p1) + (p2 + p3)) + ((p4 + p5) + (p6 + p7));

        const unsigned b0 = cvt_pk_bf16(p0, p1), b1 = cvt_pk_bf16(p2, p3);
        const unsigned b2 = cvt_pk_bf16(p4, p5), b3 = cvt_pk_bf16(p6, p7);
        const unsigned x0 = __shfl((int)b0, srcA), x1 = __shfl((int)b1, srcA);
        const unsigned x2 = __shfl((int)b0, srcB), x3 = __shfl((int)b1, srcB);
        const unsigned y0 = __shfl((int)b2, srcA), y1 = __shfl((int)b3, srcA);
        const unsigned y2 = __shfl((int)b2, srcB), y3 = __shfl((int)b3, srcB);
        const bool lo = g < 2;
        union { unsigned u[4]; bf16x8 v; } pw;
        pw.u[0] = lo ? x0 : y0;
        pw.u[1] = lo ? x1 : y1;
        pw.u[2] = lo ? x2 : y2;
        pw.u[3] = lo ? x3 : y3;

        o = __builtin_amdgcn_mfma_f32_16x16x32_bf16(vf, pw.v, o, 0, 0, 0);

        kA = kAn; kB = kBn; vf = vfn;
    }

    s += __shfl_xor(s, 16);
    s += __shfl_xor(s, 32);

    const int q = q0 + lq;
    if (q < LDIM) {
        const float inv = 1.f / s;
#pragma unroll
        for (int r = 0; r < 4; ++r)
            Oh[((size_t)(n * 128 + h * 16 + g * 4 + r)) * LDIM + q] = o[r] * inv;
    }
}

// ---------------------------------------------------------------------------
// 5. Output projection (fp32), 8 outputs/thread.
__global__ __launch_bounds__(256) void out_proj_kernel(
        const float* __restrict__ Oh, const float* __restrict__ ow,
        const float* __restrict__ ob, float* __restrict__ out) {
    const int pt = blockIdx.x, og = blockIdx.y, n = blockIdx.z;
    const int p = pt * 256 + threadIdx.x;
    const bool valid = p < LDIM;
    const int pc = valid ? p : LDIM - 1;
    float acc[8];
#pragma unroll
    for (int k = 0; k < 8; ++k) acc[k] = 0.f;
    const float* ohp = Oh + (size_t)n * 128 * LDIM + pc;
    const int o0 = og * 8;
    for (int i = 0; i < 128; i += 4) {
        float v0 = ohp[(size_t)(i + 0) * LDIM];
        float v1 = ohp[(size_t)(i + 1) * LDIM];
        float v2 = ohp[(size_t)(i + 2) * LDIM];
        float v3 = ohp[(size_t)(i + 3) * LDIM];
#pragma unroll
        for (int k = 0; k < 8; ++k) {
            acc[k] = fmaf(ow[(o0 + k) * 128 + i + 0], v0, acc[k]);
            acc[k] = fmaf(ow[(o0 + k) * 128 + i + 1], v1, acc[k]);
            acc[k] = fmaf(ow[(o0 + k) * 128 + i + 2], v2, acc[k]);
            acc[k] = fmaf(ow[(o0 + k) * 128 + i + 3], v3, acc[k]);
        }
    }
    if (!valid) return;
#pragma unroll
    for (int k = 0; k < 8; ++k)
        out[(size_t)(n * 128 + o0 + k) * LDIM + p] = acc[k] + ob[o0 + k];
}

// ---------------------------------------------------------------------------
extern "C" void kernel_launch(void* const* d_in, const int* in_sizes, int n_in,
                              void* d_out, int out_size, void* d_ws, size_t ws_size,
                              hipStream_t stream) {
    const float* x     = (const float*)d_in[0];
    const float* qkv_w = (const float*)d_in[1];
    const float* qkv_b = (const float*)d_in[2];
    const float* out_w = (const float*)d_in[3];
    const float* out_b = (const float*)d_in[4];
    float* ws = (float*)d_ws;
    ushort_t* xsp = (ushort_t*)(ws + XS_OFF);
    ushort_t* wtp = (ushort_t*)(ws + WT_OFF);
    ushort_t* qsp = (ushort_t*)(ws + Q_OFF);
    ushort_t* ksp = (ushort_t*)(ws + K_OFF);
    ushort_t* vsp = (ushort_t*)(ws + V_OFF);
    float*    Oh  = ws + OH_OFF;
    float*    out = (float*)d_out;

    pad_split_x_kernel<<<2048, 256, 0, stream>>>(x, xsp);
    w_split_kernel<<<4320, 256, 0, stream>>>(qkv_w, wtp);
    conv_mfma_kernel<<<dim3(22, 10, NB), 128, 0, stream>>>(xsp, wtp, qkv_b,
                                                           qsp, ksp, vsp);
    attn_mfma_kernel<<<dim3(43, NB * NHH), 256, 0, stream>>>(qsp, ksp, vsp, Oh);
    out_proj_kernel<<<dim3(11, 16, NB), 256, 0, stream>>>(Oh, out_w, out_b, out);
}

// Round 7
// 151.711 us; speedup vs baseline: 1.1689x; 1.1689x over previous
//
#include <hip/hip_runtime.h>

typedef short bf16x8 __attribute__((ext_vector_type(8)));
typedef float f32x4 __attribute__((ext_vector_type(4)));
typedef unsigned short ushort_t;

// Problem constants
constexpr int NB   = 2;
constexpr int ICH  = 64;
constexpr int LDIM = 2744;   // 14^3
constexpr int LPAD = 2752;   // multiple of 32
constexpr int NHH  = 8;
constexpr int KCH  = LPAD / 8;   // 344 key-chunks for V layout

// q scale: 1/sqrt(32) * log2(e)  (exp2-domain softmax)
#define QSCL (0.17677669529663687f * 1.4426950408889634f)

// Workspace layout (float offsets)
// xs : [n][kc 8][pos 4096][8us]  (bf16 hi only)        -> 262144 f
// wt : [t 27][kc 16][oc 640][8us] (hi 0-7, lo 8-15)    -> 1105920 f
// qs : [nh 16][g 4][p 2752][8us]                       -> 704512 f
// ks : same                                            -> 704512 f
// vs : [nh 16][kc 344][dv 16][8us]                     -> 352256 f
// Oh : fp32 [n 2][128][2744]                           -> 702464 f
constexpr size_t XS_OFF = 0;
constexpr size_t WT_OFF = 262144;
constexpr size_t Q_OFF  = WT_OFF + 1105920;
constexpr size_t K_OFF  = Q_OFF + 704512;
constexpr size_t V_OFF  = K_OFF + 704512;
constexpr size_t OH_OFF = V_OFF + 352256;

__device__ __forceinline__ ushort_t bf16_rn(float x) {
    unsigned u = __float_as_uint(x);
    u += 0x7FFFu + ((u >> 16) & 1u);
    return (ushort_t)(u >> 16);
}
__device__ __forceinline__ float bf16_f(ushort_t h) {
    return __uint_as_float((unsigned)h << 16);
}
__device__ __forceinline__ float exp2_hw(float x) {
    float r;
    asm("v_exp_f32 %0, %1" : "=v"(r) : "v"(x));
    return r;
}
__device__ __forceinline__ unsigned cvt_pk_bf16(float lo, float hi) {
    unsigned r;
    asm("v_cvt_pk_bf16_f32 %0, %1, %2" : "=v"(r) : "v"(lo), "v"(hi));
    return r;
}

// ---------------------------------------------------------------------------
// 1. Pad + transpose x into chunked bf16 layout (hi only — 2-pass split).
__global__ __launch_bounds__(256) void pad_split_x_kernel(
        const float* __restrict__ x, ushort_t* __restrict__ xs) {
    int idx = blockIdx.x * 256 + threadIdx.x;      // 2*64*4096
    int n  = idx >> 18;
    int ic = (idx >> 12) & 63;
    int pos = idx & 4095;
    int z = pos >> 8, y = (pos >> 4) & 15, xx = pos & 15;
    float v = 0.f;
    if (z >= 1 && z <= 14 && y >= 1 && y <= 14 && xx >= 1 && xx <= 14)
        v = x[(n * 64 + ic) * LDIM + (z - 1) * 196 + (y - 1) * 14 + (xx - 1)];
    xs[((size_t)(n * 8 + (ic >> 3)) * 4096 + pos) * 8 + (ic & 7)] = bf16_rn(v);
}

// ---------------------------------------------------------------------------
// 2. Transpose + bf16-split weights (exact hi+lo) into chunked layout.
__global__ __launch_bounds__(256) void w_split_kernel(
        const float* __restrict__ w, ushort_t* __restrict__ wt) {
    int idx = blockIdx.x * 256 + threadIdx.x;      // 27*640*64
    int t = idx / 40960;
    int r = idx % 40960;
    int oc = r >> 6, ic = r & 63;
    float v = w[(oc * 64 + ic) * 27 + t];
    ushort_t hi = bf16_rn(v);
    float lo = v - bf16_f(hi);
    wt[((size_t)(t * 16 + (ic >> 3)) * 640 + oc) * 8 + (ic & 7)] = hi;
    wt[((size_t)(t * 16 + 8 + (ic >> 3)) * 640 + oc) * 8 + (ic & 7)] = bf16_rn(lo);
}

// ---------------------------------------------------------------------------
// 3. Conv as 27 shifted K=64 MFMA GEMM-accumulates, 2-pass split.
//    m97-style: block = 4 waves sharing one 64oc x 128p tile; W tap-slice
//    (16KB) staged in LDS (double-buffered) via 2-tap-ahead reg pipeline;
//    B (X) in regs, prefetched 1 tap ahead. One barrier per tap.
__global__ __launch_bounds__(256, 2) void conv_mfma_kernel(
        const ushort_t* __restrict__ xs, const ushort_t* __restrict__ wt,
        const float* __restrict__ b, ushort_t* __restrict__ qs,
        ushort_t* __restrict__ ks, ushort_t* __restrict__ vs) {
    __shared__ ushort_t Wls[2][8192];               // [buf][kc16][oc64][8]
    const int n = blockIdx.z, ocg = blockIdx.y;
    const int wave = threadIdx.x >> 6, lane = threadIdx.x & 63;
    const int lq = lane & 15, g = lane >> 4;
    const int p0 = blockIdx.x * 128 + wave * 32;
    const int oc0 = ocg * 64;

    int posi[2], pcol[2];
#pragma unroll
    for (int ps = 0; ps < 2; ++ps) {
        int p = p0 + ps * 16 + lq;
        pcol[ps] = p;
        int pc = p < LDIM ? p : LDIM - 1;
        int z = pc / 196, rr = pc % 196, y = rr / 14, xx = rr % 14;
        posi[ps] = z * 256 + y * 16 + xx;
    }

    const bf16x8* XB = (const bf16x8*)xs + (size_t)n * 8 * 4096;
    // W stage: wave handles kc rows wave*4 .. wave*4+3; per-lane 16B of a
    // contiguous 1KB row.
    const ushort_t* wsrc_base =
        wt + ((size_t)(wave * 4) * 640 + oc0) * 8 + (size_t)lane * 8;
    const size_t WROW = 640 * 8;        // ushorts per kc row
    const size_t WTAP = 16 * WROW;      // ushorts per tap
    const int ldst = (wave * 4) * 512 + lane * 8;   // ushort index in Wls

    f32x4 acc[4][2];
#pragma unroll
    for (int os = 0; os < 4; ++os)
#pragma unroll
        for (int ps = 0; ps < 2; ++ps)
            acc[os][ps] = (f32x4){0.f, 0.f, 0.f, 0.f};

    bf16x8 rW0, rW1, rW2, rW3;          // W(t+1) stage regs
    bf16x8 rN0, rN1, rN2, rN3;          // W(t+2) stage regs
    bf16x8 Bc00, Bc01, Bc10, Bc11, Bn00, Bn01, Bn10, Bn11;

    // Prologue: W(0) -> regs -> LDS buf0; W(1) -> regs; B(0) -> regs.
    rW0 = *(const bf16x8*)(wsrc_base + 0 * WROW);
    rW1 = *(const bf16x8*)(wsrc_base + 1 * WROW);
    rW2 = *(const bf16x8*)(wsrc_base + 2 * WROW);
    rW3 = *(const bf16x8*)(wsrc_base + 3 * WROW);
    rN0 = *(const bf16x8*)(wsrc_base + WTAP + 0 * WROW);
    rN1 = *(const bf16x8*)(wsrc_base + WTAP + 1 * WROW);
    rN2 = *(const bf16x8*)(wsrc_base + WTAP + 2 * WROW);
    rN3 = *(const bf16x8*)(wsrc_base + WTAP + 3 * WROW);
    Bc00 = XB[(size_t)(g) * 4096 + posi[0]];
    Bc01 = XB[(size_t)(4 + g) * 4096 + posi[0]];
    Bc10 = XB[(size_t)(g) * 4096 + posi[1]];
    Bc11 = XB[(size_t)(4 + g) * 4096 + posi[1]];
    *(bf16x8*)&Wls[0][ldst + 0 * 512] = rW0;
    *(bf16x8*)&Wls[0][ldst + 1 * 512] = rW1;
    *(bf16x8*)&Wls[0][ldst + 2 * 512] = rW2;
    *(bf16x8*)&Wls[0][ldst + 3 * 512] = rW3;
    __syncthreads();
    rW0 = rN0; rW1 = rN1; rW2 = rN2; rW3 = rN3;    // now hold W(1)

    for (int t = 0; t < 27; ++t) {
        const int cur = t & 1;
        // issue W(t+2) global loads (land during tap t+1's compute)
        if (t < 25) {
            const ushort_t* ws = wsrc_base + (size_t)(t + 2) * WTAP;
            rN0 = *(const bf16x8*)(ws + 0 * WROW);
            rN1 = *(const bf16x8*)(ws + 1 * WROW);
            rN2 = *(const bf16x8*)(ws + 2 * WROW);
            rN3 = *(const bf16x8*)(ws + 3 * WROW);
        }
        if (t < 26) {
            // ds_write W(t+1) (its loads landed a full tap ago)
            ushort_t* d = &Wls[cur ^ 1][ldst];
            *(bf16x8*)(d + 0 * 512) = rW0;
            *(bf16x8*)(d + 1 * 512) = rW1;
            *(bf16x8*)(d + 2 * 512) = rW2;
            *(bf16x8*)(d + 3 * 512) = rW3;
            // prefetch B(t+1)
            const int tn = t + 1;
            const int tz = tn / 9, tr = tn % 9, ty = tr / 3, tx = tr % 3;
            const int toff = tz * 256 + ty * 16 + tx;
            Bn00 = XB[(size_t)(g) * 4096 + posi[0] + toff];
            Bn01 = XB[(size_t)(4 + g) * 4096 + posi[0] + toff];
            Bn10 = XB[(size_t)(g) * 4096 + posi[1] + toff];
            Bn11 = XB[(size_t)(4 + g) * 4096 + posi[1] + toff];
        }
        // compute tap t from Wls[cur] + Bc
        const ushort_t* Wb = Wls[cur];
#pragma unroll
        for (int os = 0; os < 4; ++os) {
            const int oco = (os * 16 + lq) * 8;
            const bf16x8 ah0 = *(const bf16x8*)&Wb[(g) * 512 + oco];
            const bf16x8 ah1 = *(const bf16x8*)&Wb[(4 + g) * 512 + oco];
            const bf16x8 al0 = *(const bf16x8*)&Wb[(8 + g) * 512 + oco];
            const bf16x8 al1 = *(const bf16x8*)&Wb[(12 + g) * 512 + oco];
            f32x4 a0 = acc[os][0];
            a0 = __builtin_amdgcn_mfma_f32_16x16x32_bf16(ah0, Bc00, a0, 0, 0, 0);
            a0 = __builtin_amdgcn_mfma_f32_16x16x32_bf16(ah1, Bc01, a0, 0, 0, 0);
            a0 = __builtin_amdgcn_mfma_f32_16x16x32_bf16(al0, Bc00, a0, 0, 0, 0);
            a0 = __builtin_amdgcn_mfma_f32_16x16x32_bf16(al1, Bc01, a0, 0, 0, 0);
            acc[os][0] = a0;
            f32x4 a1 = acc[os][1];
            a1 = __builtin_amdgcn_mfma_f32_16x16x32_bf16(ah0, Bc10, a1, 0, 0, 0);
            a1 = __builtin_amdgcn_mfma_f32_16x16x32_bf16(ah1, Bc11, a1, 0, 0, 0);
            a1 = __builtin_amdgcn_mfma_f32_16x16x32_bf16(al0, Bc10, a1, 0, 0, 0);
            a1 = __builtin_amdgcn_mfma_f32_16x16x32_bf16(al1, Bc11, a1, 0, 0, 0);
            acc[os][1] = a1;
        }
        __syncthreads();
        if (t < 26) {
            rW0 = rN0; rW1 = rN1; rW2 = rN2; rW3 = rN3;
            Bc00 = Bn00; Bc01 = Bn01; Bc10 = Bn10; Bc11 = Bn11;
        }
    }

    // Epilogue: bias + route to qs/ks/vs (block-uniform in ocg).
#pragma unroll
    for (int os = 0; os < 4; ++os) {
#pragma unroll
        for (int ps = 0; ps < 2; ++ps) {
            if (pcol[ps] >= LDIM) continue;
            const int p = pcol[ps];
#pragma unroll
            for (int i = 0; i < 4; ++i) {
                const int oc = oc0 + os * 16 + g * 4 + i;
                const float val = acc[os][ps][i] + b[oc];
                if (oc0 < 256) {          // q, pre-scaled into exp2 domain
                    const int h = oc >> 5, d = oc & 31;
                    qs[((size_t)((n * NHH + h) * 4 + (d >> 3)) * LPAD + p) * 8 + (d & 7)] =
                        bf16_rn(val * QSCL);
                } else if (oc0 < 512) {   // k
                    const int c = oc - 256, h = c >> 5, d = c & 31;
                    ks[((size_t)((n * NHH + h) * 4 + (d >> 3)) * LPAD + p) * 8 + (d & 7)] =
                        bf16_rn(val);
                } else {                  // v
                    const int c = oc - 512, h = c >> 4, dv = c & 15;
                    vs[((size_t)((n * NHH + h) * KCH + (p >> 3)) * 16 + dv) * 8 + (p & 7)] =
                        bf16_rn(val);
                }
            }
        }
    }
}

// ---------------------------------------------------------------------------
// 4. Flash attention, bf16 MFMA, no-max exp2 softmax, cvt_pk packing,
//    next-tile K/V register prefetch (unchanged from r5/r6).
__global__ __launch_bounds__(256) void attn_mfma_kernel(
        const ushort_t* __restrict__ qs, const ushort_t* __restrict__ ks,
        const ushort_t* __restrict__ vs, float* __restrict__ Oh) {
    const int nh = blockIdx.y, n = nh >> 3, h = nh & 7;
    const int wave = threadIdx.x >> 6, lane = threadIdx.x & 63;
    const int lq = lane & 15, g = lane >> 4;
    const int q0 = blockIdx.x * 64 + wave * 16;

    const bf16x8* QS = (const bf16x8*)qs;
    const bf16x8 qf = QS[((size_t)nh * 4 + g) * LPAD + q0 + lq];
    const bf16x8* KS = (const bf16x8*)ks + (size_t)nh * 4 * LPAD + (size_t)g * LPAD;
    const bf16x8* VS = (const bf16x8*)vs + (size_t)nh * KCH * 16 + lq;

    f32x4 o = {0.f, 0.f, 0.f, 0.f};
    float s = 0.f;
    const int srcA = lq + 32 * (g & 1);
    const int srcB = srcA + 16;

    bf16x8 kA = KS[lq];
    bf16x8 kB = KS[16 + lq];
    bf16x8 vf = VS[(size_t)g * 16];

    for (int kb = 0; kb < LDIM; kb += 32) {
        const int nb = (kb + 32 < LDIM) ? kb + 32 : kb;   // prefetch (clamped)
        bf16x8 kAn = KS[nb + lq];
        bf16x8 kBn = KS[nb + 16 + lq];
        bf16x8 vfn = VS[(size_t)((nb >> 3) + g) * 16];

        const f32x4 z = {0.f, 0.f, 0.f, 0.f};
        f32x4 st0 = __builtin_amdgcn_mfma_f32_16x16x32_bf16(kA, qf, z, 0, 0, 0);
        f32x4 st1 = __builtin_amdgcn_mfma_f32_16x16x32_bf16(kB, qf, z, 0, 0, 0);

        float p0 = exp2_hw(st0[0]), p1 = exp2_hw(st0[1]);
        float p2 = exp2_hw(st0[2]), p3 = exp2_hw(st0[3]);
        float p4 = exp2_hw(st1[0]), p5 = exp2_hw(st1[1]);
        float p6 = exp2_hw(st1[2]), p7 = exp2_hw(st1[3]);

        if (kb + 32 > LDIM) {                 // mask tail keys (>= 2744)
            if (kb + 4 * g + 0  >= LDIM) p0 = 0.f;
            if (kb + 4 * g + 1  >= LDIM) p1 = 0.f;
            if (kb + 4 * g + 2  >= LDIM) p2 = 0.f;
            if (kb + 4 * g + 3  >= LDIM) p3 = 0.f;
            if (kb + 16 + 4 * g + 0 >= LDIM) p4 = 0.f;
            if (kb + 16 + 4 * g + 1 >= LDIM) p5 = 0.f;
            if (kb + 16 + 4 * g + 2 >= LDIM) p6 = 0.f;
            if (kb + 16 + 4 * g + 3 >= LDIM) p7 = 0.f;
        }

        s += ((p0 + p1) + (p2 + p3)) + ((p4 + p5) + (p6 + p7));

        const unsigned b0 = cvt_pk_bf16(p0, p1), b1 = cvt_pk_bf16(p2, p3);
        const unsigned b2 = cvt_pk_bf16(p4, p5), b3 = cvt_pk_bf16(p6, p7);
        const unsigned x0 = __shfl((int)b0, srcA), x1 = __shfl((int)b1, srcA);
        const unsigned x2 = __shfl((int)b0, srcB), x3 = __shfl((int)b1, srcB);
        const unsigned y0 = __shfl((int)b2, srcA), y1 = __shfl((int)b3, srcA);
        const unsigned y2 = __shfl((int)b2, srcB), y3 = __shfl((int)b3, srcB);
        const bool lo = g < 2;
        union { unsigned u[4]; bf16x8 v; } pw;
        pw.u[0] = lo ? x0 : y0;
        pw.u[1] = lo ? x1 : y1;
        pw.u[2] = lo ? x2 : y2;
        pw.u[3] = lo ? x3 : y3;

        o = __builtin_amdgcn_mfma_f32_16x16x32_bf16(vf, pw.v, o, 0, 0, 0);

        kA = kAn; kB = kBn; vf = vfn;
    }

    s += __shfl_xor(s, 16);
    s += __shfl_xor(s, 32);

    const int q = q0 + lq;
    if (q < LDIM) {
        const float inv = 1.f / s;
#pragma unroll
        for (int r = 0; r < 4; ++r)
            Oh[((size_t)(n * 128 + h * 16 + g * 4 + r)) * LDIM + q] = o[r] * inv;
    }
}

// ---------------------------------------------------------------------------
// 5. Output projection (fp32), 8 outputs/thread.
__global__ __launch_bounds__(256) void out_proj_kernel(
        const float* __restrict__ Oh, const float* __restrict__ ow,
        const float* __restrict__ ob, float* __restrict__ out) {
    const int pt = blockIdx.x, og = blockIdx.y, n = blockIdx.z;
    const int p = pt * 256 + threadIdx.x;
    const bool valid = p < LDIM;
    const int pc = valid ? p : LDIM - 1;
    float acc[8];
#pragma unroll
    for (int k = 0; k < 8; ++k) acc[k] = 0.f;
    const float* ohp = Oh + (size_t)n * 128 * LDIM + pc;
    const int o0 = og * 8;
    for (int i = 0; i < 128; i += 4) {
        float v0 = ohp[(size_t)(i + 0) * LDIM];
        float v1 = ohp[(size_t)(i + 1) * LDIM];
        float v2 = ohp[(size_t)(i + 2) * LDIM];
        float v3 = ohp[(size_t)(i + 3) * LDIM];
#pragma unroll
        for (int k = 0; k < 8; ++k) {
            acc[k] = fmaf(ow[(o0 + k) * 128 + i + 0], v0, acc[k]);
            acc[k] = fmaf(ow[(o0 + k) * 128 + i + 1], v1, acc[k]);
            acc[k] = fmaf(ow[(o0 + k) * 128 + i + 2], v2, acc[k]);
            acc[k] = fmaf(ow[(o0 + k) * 128 + i + 3], v3, acc[k]);
        }
    }
    if (!valid) return;
#pragma unroll
    for (int k = 0; k < 8; ++k)
        out[(size_t)(n * 128 + o0 + k) * LDIM + p] = acc[k] + ob[o0 + k];
}

// ---------------------------------------------------------------------------
extern "C" void kernel_launch(void* const* d_in, const int* in_sizes, int n_in,
                              void* d_out, int out_size, void* d_ws, size_t ws_size,
                              hipStream_t stream) {
    const float* x     = (const float*)d_in[0];
    const float* qkv_w = (const float*)d_in[1];
    const float* qkv_b = (const float*)d_in[2];
    const float* out_w = (const float*)d_in[3];
    const float* out_b = (const float*)d_in[4];
    float* ws = (float*)d_ws;
    ushort_t* xsp = (ushort_t*)(ws + XS_OFF);
    ushort_t* wtp = (ushort_t*)(ws + WT_OFF);
    ushort_t* qsp = (ushort_t*)(ws + Q_OFF);
    ushort_t* ksp = (ushort_t*)(ws + K_OFF);
    ushort_t* vsp = (ushort_t*)(ws + V_OFF);
    float*    Oh  = ws + OH_OFF;
    float*    out = (float*)d_out;

    pad_split_x_kernel<<<2048, 256, 0, stream>>>(x, xsp);
    w_split_kernel<<<4320, 256, 0, stream>>>(qkv_w, wtp);
    conv_mfma_kernel<<<dim3(22, 10, NB), 256, 0, stream>>>(xsp, wtp, qkv_b,
                                                           qsp, ksp, vsp);
    attn_mfma_kernel<<<dim3(43, NB * NHH), 256, 0, stream>>>(qsp, ksp, vsp, Oh);
    out_proj_kernel<<<dim3(11, 16, NB), 256, 0, stream>>>(Oh, out_w, out_b, out);
}

// Round 8
// 148.049 us; speedup vs baseline: 1.1978x; 1.0247x over previous
//
#include <hip/hip_runtime.h>

typedef short bf16x8 __attribute__((ext_vector_type(8)));
typedef float f32x4 __attribute__((ext_vector_type(4)));
typedef unsigned short ushort_t;

// Problem constants
constexpr int NB   = 2;
constexpr int ICH  = 64;
constexpr int LDIM = 2744;   // 14^3
constexpr int LPAD = 2752;   // multiple of 32
constexpr int NHH  = 8;
constexpr int KCH  = LPAD / 8;   // 344 key-chunks for V layout
constexpr int KSPL = 2;          // key split
constexpr int KHALF = LPAD / KSPL;       // 1376 keys (43 tiles) per split

// q scale: 1/sqrt(32) * log2(e)  (exp2-domain softmax)
#define QSCL (0.17677669529663687f * 1.4426950408889634f)

// Workspace layout (float offsets)
constexpr size_t XS_OFF = 0;                      // 262144 f
constexpr size_t WT_OFF = 262144;                 // 1105920 f
constexpr size_t Q_OFF  = WT_OFF + 1105920;       // 704512 f
constexpr size_t K_OFF  = Q_OFF + 704512;         // 704512 f
constexpr size_t V_OFF  = K_OFF + 704512;         // 352256 f
constexpr size_t OH_OFF = V_OFF + 352256;         // 702464 f
constexpr size_t PO_OFF = OH_OFF + 702464;        // 16*2*16*2752 = 1409024 f
constexpr size_t PS_OFF = PO_OFF + 1409024;       // 16*2*2752   = 88064 f
// total ~ 5.33M floats = 21.3 MB

__device__ __forceinline__ ushort_t bf16_rn(float x) {
    unsigned u = __float_as_uint(x);
    u += 0x7FFFu + ((u >> 16) & 1u);
    return (ushort_t)(u >> 16);
}
__device__ __forceinline__ float bf16_f(ushort_t h) {
    return __uint_as_float((unsigned)h << 16);
}
__device__ __forceinline__ float exp2_hw(float x) {
    float r;
    asm("v_exp_f32 %0, %1" : "=v"(r) : "v"(x));
    return r;
}
__device__ __forceinline__ unsigned cvt_pk_bf16(float lo, float hi) {
    unsigned r;
    asm("v_cvt_pk_bf16_f32 %0, %1, %2" : "=v"(r) : "v"(lo), "v"(hi));
    return r;
}

// ---------------------------------------------------------------------------
// 1. Pad + transpose x into chunked bf16 layout (hi only — 2-pass split).
__global__ __launch_bounds__(256) void pad_split_x_kernel(
        const float* __restrict__ x, ushort_t* __restrict__ xs) {
    int idx = blockIdx.x * 256 + threadIdx.x;      // 2*64*4096
    int n  = idx >> 18;
    int ic = (idx >> 12) & 63;
    int pos = idx & 4095;
    int z = pos >> 8, y = (pos >> 4) & 15, xx = pos & 15;
    float v = 0.f;
    if (z >= 1 && z <= 14 && y >= 1 && y <= 14 && xx >= 1 && xx <= 14)
        v = x[(n * 64 + ic) * LDIM + (z - 1) * 196 + (y - 1) * 14 + (xx - 1)];
    xs[((size_t)(n * 8 + (ic >> 3)) * 4096 + pos) * 8 + (ic & 7)] = bf16_rn(v);
}

// ---------------------------------------------------------------------------
// 2. Transpose + bf16-split weights (exact hi+lo) into chunked layout.
__global__ __launch_bounds__(256) void w_split_kernel(
        const float* __restrict__ w, ushort_t* __restrict__ wt) {
    int idx = blockIdx.x * 256 + threadIdx.x;      // 27*640*64
    int t = idx / 40960;
    int r = idx % 40960;
    int oc = r >> 6, ic = r & 63;
    float v = w[(oc * 64 + ic) * 27 + t];
    ushort_t hi = bf16_rn(v);
    float lo = v - bf16_f(hi);
    wt[((size_t)(t * 16 + (ic >> 3)) * 640 + oc) * 8 + (ic & 7)] = hi;
    wt[((size_t)(t * 16 + 8 + (ic >> 3)) * 640 + oc) * 8 + (ic & 7)] = bf16_rn(lo);
}

// ---------------------------------------------------------------------------
// 3. Conv as 27 shifted K=64 MFMA GEMM-accumulates, 2-pass split.
//    (unchanged from r7 except the K-storage slot permutation in the
//    epilogue: stored slot within each 32-key tile = 4g+j (j<4) or
//    16+4g+j-4 (j>=4) for key offset 8g+j, making the attention PV
//    B-fragment lane-local — zero shuffles.)
__global__ __launch_bounds__(256, 2) void conv_mfma_kernel(
        const ushort_t* __restrict__ xs, const ushort_t* __restrict__ wt,
        const float* __restrict__ b, ushort_t* __restrict__ qs,
        ushort_t* __restrict__ ks, ushort_t* __restrict__ vs) {
    __shared__ ushort_t Wls[2][8192];               // [buf][kc16][oc64][8]
    const int n = blockIdx.z, ocg = blockIdx.y;
    const int wave = threadIdx.x >> 6, lane = threadIdx.x & 63;
    const int lq = lane & 15, g = lane >> 4;
    const int p0 = blockIdx.x * 128 + wave * 32;
    const int oc0 = ocg * 64;

    int posi[2], pcol[2];
#pragma unroll
    for (int ps = 0; ps < 2; ++ps) {
        int p = p0 + ps * 16 + lq;
        pcol[ps] = p;
        int pc = p < LDIM ? p : LDIM - 1;
        int z = pc / 196, rr = pc % 196, y = rr / 14, xx = rr % 14;
        posi[ps] = z * 256 + y * 16 + xx;
    }

    const bf16x8* XB = (const bf16x8*)xs + (size_t)n * 8 * 4096;
    const ushort_t* wsrc_base =
        wt + ((size_t)(wave * 4) * 640 + oc0) * 8 + (size_t)lane * 8;
    const size_t WROW = 640 * 8;
    const size_t WTAP = 16 * WROW;
    const int ldst = (wave * 4) * 512 + lane * 8;

    f32x4 acc[4][2];
#pragma unroll
    for (int os = 0; os < 4; ++os)
#pragma unroll
        for (int ps = 0; ps < 2; ++ps)
            acc[os][ps] = (f32x4){0.f, 0.f, 0.f, 0.f};

    bf16x8 rW0, rW1, rW2, rW3;
    bf16x8 rN0, rN1, rN2, rN3;
    bf16x8 Bc00, Bc01, Bc10, Bc11, Bn00, Bn01, Bn10, Bn11;

    rW0 = *(const bf16x8*)(wsrc_base + 0 * WROW);
    rW1 = *(const bf16x8*)(wsrc_base + 1 * WROW);
    rW2 = *(const bf16x8*)(wsrc_base + 2 * WROW);
    rW3 = *(const bf16x8*)(wsrc_base + 3 * WROW);
    rN0 = *(const bf16x8*)(wsrc_base + WTAP + 0 * WROW);
    rN1 = *(const bf16x8*)(wsrc_base + WTAP + 1 * WROW);
    rN2 = *(const bf16x8*)(wsrc_base + WTAP + 2 * WROW);
    rN3 = *(const bf16x8*)(wsrc_base + WTAP + 3 * WROW);
    Bc00 = XB[(size_t)(g) * 4096 + posi[0]];
    Bc01 = XB[(size_t)(4 + g) * 4096 + posi[0]];
    Bc10 = XB[(size_t)(g) * 4096 + posi[1]];
    Bc11 = XB[(size_t)(4 + g) * 4096 + posi[1]];
    *(bf16x8*)&Wls[0][ldst + 0 * 512] = rW0;
    *(bf16x8*)&Wls[0][ldst + 1 * 512] = rW1;
    *(bf16x8*)&Wls[0][ldst + 2 * 512] = rW2;
    *(bf16x8*)&Wls[0][ldst + 3 * 512] = rW3;
    __syncthreads();
    rW0 = rN0; rW1 = rN1; rW2 = rN2; rW3 = rN3;

    for (int t = 0; t < 27; ++t) {
        const int cur = t & 1;
        if (t < 25) {
            const ushort_t* wsp = wsrc_base + (size_t)(t + 2) * WTAP;
            rN0 = *(const bf16x8*)(wsp + 0 * WROW);
            rN1 = *(const bf16x8*)(wsp + 1 * WROW);
            rN2 = *(const bf16x8*)(wsp + 2 * WROW);
            rN3 = *(const bf16x8*)(wsp + 3 * WROW);
        }
        if (t < 26) {
            ushort_t* d = &Wls[cur ^ 1][ldst];
            *(bf16x8*)(d + 0 * 512) = rW0;
            *(bf16x8*)(d + 1 * 512) = rW1;
            *(bf16x8*)(d + 2 * 512) = rW2;
            *(bf16x8*)(d + 3 * 512) = rW3;
            const int tn = t + 1;
            const int tz = tn / 9, tr = tn % 9, ty = tr / 3, tx = tr % 3;
            const int toff = tz * 256 + ty * 16 + tx;
            Bn00 = XB[(size_t)(g) * 4096 + posi[0] + toff];
            Bn01 = XB[(size_t)(4 + g) * 4096 + posi[0] + toff];
            Bn10 = XB[(size_t)(g) * 4096 + posi[1] + toff];
            Bn11 = XB[(size_t)(4 + g) * 4096 + posi[1] + toff];
        }
        const ushort_t* Wb = Wls[cur];
#pragma unroll
        for (int os = 0; os < 4; ++os) {
            const int oco = (os * 16 + lq) * 8;
            const bf16x8 ah0 = *(const bf16x8*)&Wb[(g) * 512 + oco];
            const bf16x8 ah1 = *(const bf16x8*)&Wb[(4 + g) * 512 + oco];
            const bf16x8 al0 = *(const bf16x8*)&Wb[(8 + g) * 512 + oco];
            const bf16x8 al1 = *(const bf16x8*)&Wb[(12 + g) * 512 + oco];
            f32x4 a0 = acc[os][0];
            a0 = __builtin_amdgcn_mfma_f32_16x16x32_bf16(ah0, Bc00, a0, 0, 0, 0);
            a0 = __builtin_amdgcn_mfma_f32_16x16x32_bf16(ah1, Bc01, a0, 0, 0, 0);
            a0 = __builtin_amdgcn_mfma_f32_16x16x32_bf16(al0, Bc00, a0, 0, 0, 0);
            a0 = __builtin_amdgcn_mfma_f32_16x16x32_bf16(al1, Bc01, a0, 0, 0, 0);
            acc[os][0] = a0;
            f32x4 a1 = acc[os][1];
            a1 = __builtin_amdgcn_mfma_f32_16x16x32_bf16(ah0, Bc10, a1, 0, 0, 0);
            a1 = __builtin_amdgcn_mfma_f32_16x16x32_bf16(ah1, Bc11, a1, 0, 0, 0);
            a1 = __builtin_amdgcn_mfma_f32_16x16x32_bf16(al0, Bc10, a1, 0, 0, 0);
            a1 = __builtin_amdgcn_mfma_f32_16x16x32_bf16(al1, Bc11, a1, 0, 0, 0);
            acc[os][1] = a1;
        }
        __syncthreads();
        if (t < 26) {
            rW0 = rN0; rW1 = rN1; rW2 = rN2; rW3 = rN3;
            Bc00 = Bn00; Bc01 = Bn01; Bc10 = Bn10; Bc11 = Bn11;
        }
    }

    // Epilogue: bias + route to qs/ks/vs (block-uniform in ocg).
#pragma unroll
    for (int os = 0; os < 4; ++os) {
#pragma unroll
        for (int ps = 0; ps < 2; ++ps) {
            if (pcol[ps] >= LDIM) continue;
            const int p = pcol[ps];
#pragma unroll
            for (int i = 0; i < 4; ++i) {
                const int oc = oc0 + os * 16 + g * 4 + i;
                const float val = acc[os][ps][i] + b[oc];
                if (oc0 < 256) {          // q, pre-scaled into exp2 domain
                    const int h = oc >> 5, d = oc & 31;
                    qs[((size_t)((n * NHH + h) * 4 + (d >> 3)) * LPAD + p) * 8 + (d & 7)] =
                        bf16_rn(val * QSCL);
                } else if (oc0 < 512) {   // k -> permuted slot within 32-tile
                    const int c = oc - 256, h = c >> 5, d = c & 31;
                    const int o = p & 31, gg = o >> 3, jj = o & 7;
                    const int slot = (jj < 4) ? (gg * 4 + jj)
                                              : (16 + gg * 4 + (jj - 4));
                    const int sp = (p & ~31) + slot;
                    ks[((size_t)((n * NHH + h) * 4 + (d >> 3)) * LPAD + sp) * 8 + (d & 7)] =
                        bf16_rn(val);
                } else {                  // v (natural key order)
                    const int c = oc - 512, h = c >> 4, dv = c & 15;
                    vs[((size_t)((n * NHH + h) * KCH + (p >> 3)) * 16 + dv) * 8 + (p & 7)] =
                        bf16_rn(val);
                }
            }
        }
    }
}

// ---------------------------------------------------------------------------
// 4. Flash attention partial, bf16 MFMA, no-max exp2 softmax.
//    Zero-shuffle PV thanks to permuted K storage; key-split KSPL=2 with
//    linear partial combine (no-max softmax => partials are linear).
__global__ __launch_bounds__(256) void attn_mfma_kernel(
        const ushort_t* __restrict__ qs, const ushort_t* __restrict__ ks,
        const ushort_t* __restrict__ vs, float* __restrict__ po,
        float* __restrict__ psum) {
    const int nh = blockIdx.z;
    const int kspl = blockIdx.y;
    const int wave = threadIdx.x >> 6, lane = threadIdx.x & 63;
    const int lq = lane & 15, g = lane >> 4;
    const int q0 = blockIdx.x * 64 + wave * 16;

    const bf16x8* QS = (const bf16x8*)qs;
    const bf16x8 qf = QS[((size_t)nh * 4 + g) * LPAD + q0 + lq];
    const bf16x8* KS = (const bf16x8*)ks + ((size_t)nh * 4 + g) * LPAD +
                       (size_t)kspl * KHALF;
    const bf16x8* VS = (const bf16x8*)vs + (size_t)nh * KCH * 16 +
                       (size_t)kspl * (KHALF / 8) * 16 + lq;

    f32x4 o = {0.f, 0.f, 0.f, 0.f};
    float s = 0.f;
    const int NT = KHALF / 32;                 // 43 tiles
    const int tail_i = (kspl == KSPL - 1) ? NT - 1 : -1;

    bf16x8 kA = KS[lq];
    bf16x8 kB = KS[16 + lq];
    bf16x8 vf = VS[(size_t)g * 16];

    for (int i = 0; i < NT; ++i) {
        const int nb = (i + 1 < NT) ? i + 1 : i;    // clamped prefetch
        bf16x8 kAn = KS[nb * 32 + lq];
        bf16x8 kBn = KS[nb * 32 + 16 + lq];
        bf16x8 vfn = VS[(size_t)(nb * 4 + g) * 16];

        const f32x4 z = {0.f, 0.f, 0.f, 0.f};
        __builtin_amdgcn_s_setprio(1);
        f32x4 st0 = __builtin_amdgcn_mfma_f32_16x16x32_bf16(kA, qf, z, 0, 0, 0);
        f32x4 st1 = __builtin_amdgcn_mfma_f32_16x16x32_bf16(kB, qf, z, 0, 0, 0);
        __builtin_amdgcn_s_setprio(0);

        float p0 = exp2_hw(st0[0]), p1 = exp2_hw(st0[1]);
        float p2 = exp2_hw(st0[2]), p3 = exp2_hw(st0[3]);
        float p4 = exp2_hw(st1[0]), p5 = exp2_hw(st1[1]);
        float p6 = exp2_hw(st1[2]), p7 = exp2_hw(st1[3]);

        if (i == tail_i && g == 3) {           // keys 2744..2751 == g=3 slots
            p0 = p1 = p2 = p3 = p4 = p5 = p6 = p7 = 0.f;
        }

        s += ((p0 + p1) + (p2 + p3)) + ((p4 + p5) + (p6 + p7));

        union { unsigned u[4]; bf16x8 v; } pw;
        pw.u[0] = cvt_pk_bf16(p0, p1);         // keys 8g+0, 8g+1
        pw.u[1] = cvt_pk_bf16(p2, p3);         // keys 8g+2, 8g+3
        pw.u[2] = cvt_pk_bf16(p4, p5);         // keys 8g+4, 8g+5
        pw.u[3] = cvt_pk_bf16(p6, p7);         // keys 8g+6, 8g+7

        __builtin_amdgcn_s_setprio(1);
        o = __builtin_amdgcn_mfma_f32_16x16x32_bf16(vf, pw.v, o, 0, 0, 0);
        __builtin_amdgcn_s_setprio(0);

        kA = kAn; kB = kBn; vf = vfn;
    }

    const int q = q0 + lq;
    if (q < LDIM) {
        // partial O (un-normalized) and partial sum
        float* pb = po + (((size_t)nh * KSPL + kspl) * 16) * LPAD + q;
#pragma unroll
        for (int r = 0; r < 4; ++r)
            pb[(size_t)(g * 4 + r) * LPAD] = o[r];
        // s reduce across the 4 g-groups (same q)
        s += __shfl_xor(s, 16);
        s += __shfl_xor(s, 32);
        if (g == 0)
            psum[((size_t)nh * KSPL + kspl) * LPAD + q] = s;
    }
}

// ---------------------------------------------------------------------------
// 5. Combine key-split partials (linear): Oh = (o0+o1)/(s0+s1).
__global__ __launch_bounds__(256) void attn_combine_kernel(
        const float* __restrict__ po, const float* __restrict__ psum,
        float* __restrict__ Oh) {
    const int q = blockIdx.x * 256 + threadIdx.x;
    const int nh = blockIdx.y, n = nh >> 3, h = nh & 7;
    if (q >= LDIM) return;
    const float s = psum[((size_t)nh * KSPL + 0) * LPAD + q] +
                    psum[((size_t)nh * KSPL + 1) * LPAD + q];
    const float inv = 1.f / s;
    const float* p0 = po + (((size_t)nh * KSPL + 0) * 16) * LPAD + q;
    const float* p1 = po + (((size_t)nh * KSPL + 1) * 16) * LPAD + q;
#pragma unroll
    for (int dv = 0; dv < 16; ++dv) {
        const float v = p0[(size_t)dv * LPAD] + p1[(size_t)dv * LPAD];
        Oh[((size_t)(n * 128 + h * 16 + dv)) * LDIM + q] = v * inv;
    }
}

// ---------------------------------------------------------------------------
// 6. Output projection (fp32), 8 outputs/thread.
__global__ __launch_bounds__(256) void out_proj_kernel(
        const float* __restrict__ Oh, const float* __restrict__ ow,
        const float* __restrict__ ob, float* __restrict__ out) {
    const int pt = blockIdx.x, og = blockIdx.y, n = blockIdx.z;
    const int p = pt * 256 + threadIdx.x;
    const bool valid = p < LDIM;
    const int pc = valid ? p : LDIM - 1;
    float acc[8];
#pragma unroll
    for (int k = 0; k < 8; ++k) acc[k] = 0.f;
    const float* ohp = Oh + (size_t)n * 128 * LDIM + pc;
    const int o0 = og * 8;
    for (int i = 0; i < 128; i += 4) {
        float v0 = ohp[(size_t)(i + 0) * LDIM];
        float v1 = ohp[(size_t)(i + 1) * LDIM];
        float v2 = ohp[(size_t)(i + 2) * LDIM];
        float v3 = ohp[(size_t)(i + 3) * LDIM];
#pragma unroll
        for (int k = 0; k < 8; ++k) {
            acc[k] = fmaf(ow[(o0 + k) * 128 + i + 0], v0, acc[k]);
            acc[k] = fmaf(ow[(o0 + k) * 128 + i + 1], v1, acc[k]);
            acc[k] = fmaf(ow[(o0 + k) * 128 + i + 2], v2, acc[k]);
            acc[k] = fmaf(ow[(o0 + k) * 128 + i + 3], v3, acc[k]);
        }
    }
    if (!valid) return;
#pragma unroll
    for (int k = 0; k < 8; ++k)
        out[(size_t)(n * 128 + o0 + k) * LDIM + p] = acc[k] + ob[o0 + k];
}

// ---------------------------------------------------------------------------
extern "C" void kernel_launch(void* const* d_in, const int* in_sizes, int n_in,
                              void* d_out, int out_size, void* d_ws, size_t ws_size,
                              hipStream_t stream) {
    const float* x     = (const float*)d_in[0];
    const float* qkv_w = (const float*)d_in[1];
    const float* qkv_b = (const float*)d_in[2];
    const float* out_w = (const float*)d_in[3];
    const float* out_b = (const float*)d_in[4];
    float* ws = (float*)d_ws;
    ushort_t* xsp = (ushort_t*)(ws + XS_OFF);
    ushort_t* wtp = (ushort_t*)(ws + WT_OFF);
    ushort_t* qsp = (ushort_t*)(ws + Q_OFF);
    ushort_t* ksp = (ushort_t*)(ws + K_OFF);
    ushort_t* vsp = (ushort_t*)(ws + V_OFF);
    float*    Oh  = ws + OH_OFF;
    float*    pop = ws + PO_OFF;
    float*    psp = ws + PS_OFF;
    float*    out = (float*)d_out;

    pad_split_x_kernel<<<2048, 256, 0, stream>>>(x, xsp);
    w_split_kernel<<<4320, 256, 0, stream>>>(qkv_w, wtp);
    conv_mfma_kernel<<<dim3(22, 10, NB), 256, 0, stream>>>(xsp, wtp, qkv_b,
                                                           qsp, ksp, vsp);
    attn_mfma_kernel<<<dim3(43, KSPL, NB * NHH), 256, 0, stream>>>(qsp, ksp, vsp,
                                                                   pop, psp);
    attn_combine_kernel<<<dim3(11, NB * NHH), 256, 0, stream>>>(pop, psp, Oh);
    out_proj_kernel<<<dim3(11, 16, NB), 256, 0, stream>>>(Oh, out_w, out_b, out);
}